// Round 4
// baseline (406.083 us; speedup 1.0000x reference)
//
#include <hip/hip_runtime.h>

// =====================================================================
// QuadraticChargesEnergyReadout — R6b: resubmit of R6 (infra failure,
// "container failed twice" — no counters, no correctness signal).
// R6: depth-2 prefetch + 3 waves/SIMD.
// R5 post-mortem: depth-1 prefetch gained only 8 us. Little's law on
// the measured ~1.8 TB/s says avg in-flight is only ~2.6 KB/CU (need
// ~50+ KB/CU): the depth-1 window at 2 waves/SIMD collapses whenever
// the scheduler sinks a load cluster, and there's no TLP to cover it.
// R6 brute-forces queue depth: TWO full rotating prefetch sets per
// wave (12 loads = 12 KB always outstanding) and occupancy 2->3
// waves/SIMD (__launch_bounds__(256,3), live VGPR ~146 < 168 cap).
// Target in-flight 12 waves/CU x 12 KB = 144 KB/CU.
// Memory-bound floor: ~271 MB traffic -> ~43 us.
// =====================================================================

#define NNODES 131072
#define TBLK 256
#define NODES_PER_PASS 8          // (TBLK/32) nodes per block-pass
#define PASSES 8
#define NPB (NODES_PER_PASS * PASSES)   // 64 nodes per block

// ---------------- precompute 1: per-block partial coefficients --------
// partial[b][k][w], k 0..5 = s.s monomials {a2,ab,b2,a,b,1} vs W_ss,
// 6..8 = {Sg2,Sgd,Sd2} vs W_vv, 9..14 = {ag,ad,bg,bd,g,d} vs W_sv/W_vs.
__global__ void precompute_coeff(
    const float* __restrict__ Wa_s, const float* __restrict__ Wa_v,
    const float* __restrict__ b_a,  const float* __restrict__ Wb_s,
    const float* __restrict__ Wb_v, const float* __restrict__ b_b,
    const float* __restrict__ W_ss, const float* __restrict__ W_vv,
    const float* __restrict__ W_sv, const float* __restrict__ W_vs,
    float* __restrict__ partial)
{
  __shared__ float As[32], Bs[32], Cc[32], Avv[32], Bvv[32];
  __shared__ float red[8][480];
  const int t = threadIdx.x;                     // 256 threads, 32 blocks
  if (t < 32) {
    As[t] = Wa_s[t]; Bs[t] = Wb_s[t]; Cc[t] = b_a[t] + b_b[t];
    Avv[t] = Wa_v[t]; Bvv[t] = Wb_v[t];
  }
  __syncthreads();
  const int w = t & 31;
  const int grp = t >> 5;
  const int chunk = blockIdx.x * 8 + grp;        // 256 chunks x 4 pairs
  float acc[15];
  #pragma unroll
  for (int k = 0; k < 15; ++k) acc[k] = 0.f;
  #pragma unroll
  for (int j = 0; j < 4; ++j) {
    const int p = chunk * 4 + j;                 // pair = u*32+v
    const int u = p >> 5, v = p & 31;
    const float wss = W_ss[p * 32 + w];
    const float wvv = W_vv[p * 32 + w];
    const float wsv = W_sv[p * 32 + w];
    const float wvs = W_vs[p * 32 + w];
    const float au = As[u], bu = Bs[u], cu = Cc[u], pu = Avv[u], qu = Bvv[u];
    const float av = As[v], bv = Bs[v], cv = Cc[v], pv = Avv[v], qv = Bvv[v];
    acc[0]  = fmaf(au * av, wss, acc[0]);
    acc[1]  = fmaf(au * bv + bu * av, wss, acc[1]);
    acc[2]  = fmaf(bu * bv, wss, acc[2]);
    acc[3]  = fmaf(au * cv + cu * av, wss, acc[3]);
    acc[4]  = fmaf(bu * cv + cu * bv, wss, acc[4]);
    acc[5]  = fmaf(cu * cv, wss, acc[5]);
    acc[6]  = fmaf(pu * pv, wvv, acc[6]);
    acc[7]  = fmaf(pu * qv + qu * pv, wvv, acc[7]);
    acc[8]  = fmaf(qu * qv, wvv, acc[8]);
    acc[9]  = fmaf(au * pv, wsv, fmaf(pu * av, wvs, acc[9]));
    acc[10] = fmaf(au * qv, wsv, fmaf(qu * av, wvs, acc[10]));
    acc[11] = fmaf(bu * pv, wsv, fmaf(pu * bv, wvs, acc[11]));
    acc[12] = fmaf(bu * qv, wsv, fmaf(qu * bv, wvs, acc[12]));
    acc[13] = fmaf(cu * pv, wsv, fmaf(pu * cv, wvs, acc[13]));
    acc[14] = fmaf(cu * qv, wsv, fmaf(qu * cv, wvs, acc[14]));
  }
  #pragma unroll
  for (int k = 0; k < 15; ++k) red[grp][k * 32 + w] = acc[k];
  __syncthreads();
  for (int kk = grp; kk < 15; kk += 8) {
    float s = 0.f;
    #pragma unroll
    for (int b = 0; b < 8; ++b) s += red[b][kk * 32 + w];
    partial[blockIdx.x * 480 + kk * 32 + w] = s;
  }
}

// ---------------- precompute 2: reduce partials, fold through Wd ------
__global__ void precompute_M(
    const float* __restrict__ Wd_s, const float* __restrict__ Wd_v,
    const float* __restrict__ partial,
    float* __restrict__ Ms, float* __restrict__ Mv)
{
  __shared__ float cf[480];
  const int t = threadIdx.x;                     // 512 threads, 1 block
  if (t < 480) {
    float s = 0.f;
    for (int b = 0; b < 32; ++b) s += partial[b * 480 + t];
    cf[t] = s;
  }
  __syncthreads();
  if (t < 128) {
    const int f = t;
    float as[9], av[6];
    #pragma unroll
    for (int k = 0; k < 9; ++k) as[k] = 0.f;
    #pragma unroll
    for (int k = 0; k < 6; ++k) av[k] = 0.f;
    for (int w = 0; w < 32; ++w) {
      const float wds = Wd_s[w * 128 + f];
      const float wdv = Wd_v[w * 128 + f];
      #pragma unroll
      for (int k = 0; k < 9; ++k) as[k] = fmaf(cf[k * 32 + w], wds, as[k]);
      #pragma unroll
      for (int k = 0; k < 6; ++k) av[k] = fmaf(cf[(9 + k) * 32 + w], wdv, av[k]);
    }
    const float sP = 1.0f / 4096.0f;                        // PW_DOWN*PW_QQ_S
    const float sQ = 0.57735026918962576451f / 4096.0f;     // *INV_SQRT3
    #pragma unroll
    for (int k = 0; k < 6; ++k) Ms[f * 16 + k] = as[k] * sP;
    #pragma unroll
    for (int k = 0; k < 3; ++k) Ms[f * 16 + 6 + k] = as[6 + k] * sQ;
    #pragma unroll
    for (int k = 0; k < 6; ++k) Mv[f * 8 + k] = av[k] * sQ;
  }
}

// ---------------- main kernel: streamed, depth-2 prefetch -------------
// Lane s (=t&31) owns features f in [4s, 4s+4):
//   s-region : float4 index  s (dense across lanes)
//   v-region : float4 index 32+3s+{0,1,2} (phase-aligned whole features;
//              stride-48B across lanes — TA-segment math shows this is
//              not the limiter, and it keeps the i=q%3 phases static)
// Coefficients Ms/Mv for the lane's 4 features: 60 loop-invariant regs.
// Two full prefetch register sets (A/B) rotate: while pass p computes,
// passes p+1 AND p+2 (12 loads, 12 KB/wave) are in flight.
__global__ __launch_bounds__(TBLK, 3) void energy_main(
    const float* __restrict__ nf,
    const float* __restrict__ ch0,
    const float* __restrict__ chi,
    const float* __restrict__ Ms,
    const float* __restrict__ Mv,
    float* __restrict__ out)
{
  static_assert(NPB * (NNODES / NPB) == NNODES, "grid covers all nodes");
  const int t    = threadIdx.x;
  const int s32  = t & 31;          // lane within the 32-lane node group
  const int gidx = t >> 5;          // 0..7: node slot within a pass

  // ---- per-lane loop-invariant coefficients ----
  float ms[4][9];
  float mv[4][6];
  {
    const float4* Ms4 = reinterpret_cast<const float4*>(Ms);  // [128][4]
    const float4* Mv4 = reinterpret_cast<const float4*>(Mv);  // [128][2]
    #pragma unroll
    for (int fl = 0; fl < 4; ++fl) {
      const int f = 4 * s32 + fl;
      const float4 a = Ms4[f * 4 + 0];
      const float4 b = Ms4[f * 4 + 1];
      const float4 c = Ms4[f * 4 + 2];
      ms[fl][0] = a.x; ms[fl][1] = a.y; ms[fl][2] = a.z; ms[fl][3] = a.w;
      ms[fl][4] = b.x; ms[fl][5] = b.y; ms[fl][6] = b.z; ms[fl][7] = b.w;
      ms[fl][8] = c.x;
      const float4 u = Mv4[f * 2 + 0];
      const float4 v = Mv4[f * 2 + 1];
      mv[fl][0] = u.x; mv[fl][1] = u.y; mv[fl][2] = u.z; mv[fl][3] = u.w;
      mv[fl][4] = v.x; mv[fl][5] = v.y;
    }
  }

  const float4* nf4 = reinterpret_cast<const float4*>(nf);
  const float4* c04 = reinterpret_cast<const float4*>(ch0);
  const float4* ci4 = reinterpret_cast<const float4*>(chi);

  const int node0 = blockIdx.x * NPB;

  float4 Axs, Av0, Av1, Av2, Ac0, Aci;
  float4 Bxs, Bv0, Bv1, Bv2, Bc0, Bci;

#define LOADSET(X, pp) do {                                        \
    const int nn_   = node0 + (pp) * NODES_PER_PASS + gidx;        \
    const size_t rb_ = (size_t)nn_ * 128;                          \
    X##c0 = c04[nn_];                                              \
    X##ci = ci4[nn_];                                              \
    X##xs = nf4[rb_ + s32];                                        \
    X##v0 = nf4[rb_ + 32 + 3 * s32 + 0];                           \
    X##v1 = nf4[rb_ + 32 + 3 * s32 + 1];                           \
    X##v2 = nf4[rb_ + 32 + 3 * s32 + 2];                           \
  } while (0)

  // ---- prologue: passes 0 and 1 in flight ----
  LOADSET(A, 0);
  LOADSET(B, 1);

  #pragma unroll
  for (int p = 0; p < PASSES; ++p) {
    // consume the set for pass p; immediately refill it for pass p+2
    float4 xs, xv0, xv1, xv2, cc0, cci;
    if ((p & 1) == 0) {
      xs = Axs; xv0 = Av0; xv1 = Av1; xv2 = Av2; cc0 = Ac0; cci = Aci;
      if (p + 2 < PASSES) LOADSET(A, p + 2);
    } else {
      xs = Bxs; xv0 = Bv0; xv1 = Bv1; xv2 = Bv2; cc0 = Bc0; cci = Bci;
      if (p + 2 < PASSES) LOADSET(B, p + 2);
    }

    const int node = node0 + p * NODES_PER_PASS + gidx;

    const float alpha = cci.x, g0 = cci.y, g1 = cci.z, g2 = cci.w;
    const float beta  = cc0.x, d0 = cc0.y, d1 = cc0.z, d2 = cc0.w;
    const float m0 = alpha * alpha, m1 = alpha * beta, m2 = beta * beta;
    const float m6 = fmaf(g0, g0, fmaf(g1, g1, g2 * g2));
    const float m7 = fmaf(g0, d0, fmaf(g1, d1, g2 * d2));
    const float m8 = fmaf(d0, d0, fmaf(d1, d1, d2 * d2));

    float e = 0.f;

    // ---- s-region: 4 features (one float4) ----
    const float xse[4] = {xs.x, xs.y, xs.z, xs.w};
    #pragma unroll
    for (int fl = 0; fl < 4; ++fl) {
      float r = ms[fl][5];
      r = fmaf(m0,    ms[fl][0], r);
      r = fmaf(m1,    ms[fl][1], r);
      r = fmaf(m2,    ms[fl][2], r);
      r = fmaf(alpha, ms[fl][3], r);
      r = fmaf(beta,  ms[fl][4], r);
      r = fmaf(m6,    ms[fl][6], r);
      r = fmaf(m7,    ms[fl][7], r);
      r = fmaf(m8,    ms[fl][8], r);
      e = fmaf(xse[fl], r, e);
    }

    // ---- v-region: 12 floats = 4 whole features, phases compile-time --
    const float xve[12] = {xv0.x, xv0.y, xv0.z, xv0.w,
                           xv1.x, xv1.y, xv1.z, xv1.w,
                           xv2.x, xv2.y, xv2.z, xv2.w};
    const float gg[3] = {g0, g1, g2};
    const float dd[3] = {d0, d1, d2};
    float P = 0.f, Q = 0.f;
    #pragma unroll
    for (int q = 0; q < 12; ++q) {
      const int i = q % 3;                       // compile-time on unroll
      P = fmaf(gg[i], xve[q], P);
      Q = fmaf(dd[i], xve[q], Q);
      if (i == 2) {                              // feature complete
        const int fl = q / 3;
        const float wP = fmaf(alpha, mv[fl][0], fmaf(beta, mv[fl][2], mv[fl][4]));
        const float wQ = fmaf(alpha, mv[fl][1], fmaf(beta, mv[fl][3], mv[fl][5]));
        e = fmaf(P, wP, fmaf(Q, wQ, e));
        P = 0.f; Q = 0.f;
      }
    }

    // ---- reduce across the 32-lane group ----
    e += __shfl_xor(e, 1);
    e += __shfl_xor(e, 2);
    e += __shfl_xor(e, 4);
    e += __shfl_xor(e, 8);
    e += __shfl_xor(e, 16);
    if (s32 == 0) out[node] = e;
  }
#undef LOADSET
}

// ---------------- launcher -------------------------------------------
extern "C" void kernel_launch(void* const* d_in, const int* in_sizes, int n_in,
                              void* d_out, int out_size, void* d_ws, size_t ws_size,
                              hipStream_t stream)
{
  const float* node_feats      = (const float*)d_in[0];
  const float* charges_0       = (const float*)d_in[1];
  const float* charges_induced = (const float*)d_in[2];
  const float* Wa_s = (const float*)d_in[8];
  const float* Wa_v = (const float*)d_in[9];
  const float* b_a  = (const float*)d_in[10];
  const float* Wb_s = (const float*)d_in[11];
  const float* Wb_v = (const float*)d_in[12];
  const float* b_b  = (const float*)d_in[13];
  const float* W_ss = (const float*)d_in[14];
  const float* W_vv = (const float*)d_in[15];
  const float* W_sv = (const float*)d_in[16];
  const float* W_vs = (const float*)d_in[17];
  const float* Wd_s = (const float*)d_in[18];
  const float* Wd_v = (const float*)d_in[19];

  float* ws      = (float*)d_ws;
  float* Ms      = ws;              // [128][16] = 2048 floats
  float* Mv      = ws + 2048;       // [128][8]  = 1024 floats
  float* partial = ws + 3072;       // [32][15][32] = 15360 floats

  precompute_coeff<<<32, 256, 0, stream>>>(Wa_s, Wa_v, b_a, Wb_s, Wb_v, b_b,
                                           W_ss, W_vv, W_sv, W_vs, partial);
  precompute_M<<<1, 512, 0, stream>>>(Wd_s, Wd_v, partial, Ms, Mv);
  energy_main<<<NNODES / NPB, TBLK, 0, stream>>>(node_feats, charges_0,
                                                 charges_induced, Ms, Mv,
                                                 (float*)d_out);
}

// Round 6
// 405.480 us; speedup vs baseline: 1.0015x; 1.0015x over previous
//
#include <hip/hip_runtime.h>

// =====================================================================
// QuadraticChargesEnergyReadout — R7b: compile-fix of R7 (nontemporal
// builtins reject HIP_vector_type — switched streaming loads to clang
// ext_vector_type vectors). Theory unchanged:
// R6 post-mortem: bounds(256,3) capped VGPR at ~84 under a ~140-reg
// live set -> scratch spills cancelled the occupancy gain; TLP theory
// never tested. Also: R0's energy_main WRITE_SIZE=54MB (output 0.5MB)
// = dirty-L3 victim writebacks from the harness's 1-GiB poison fills,
// coupled synchronously to our read stream.
// R7: (1) 64 lanes/node (2 features/lane) -> coeffs 60->30 regs, data
// 24->14/pass; live ~90 fits __launch_bounds__(256,5) (no spill,
// 20 waves/CU). (2) nontemporal loads/stores on all node streams ->
// no L2/L3 allocation, no victim writebacks. (3) depth-1 prefetch.
// Memory-bound floor: ~271 MB traffic -> ~43 us.
// =====================================================================

#define NNODES 131072
#define TBLK 256
#define WAVES_PER_BLK 4           // 4 waves = 4 nodes per pass
#define PASSES 16
#define NPB (WAVES_PER_BLK * PASSES)   // 64 nodes per block, grid 2048

typedef float f32x2 __attribute__((ext_vector_type(2)));
typedef float f32x4 __attribute__((ext_vector_type(4)));

// ---------------- precompute 1: per-block partial coefficients --------
// partial[b][k][w], k 0..5 = s.s monomials {a2,ab,b2,a,b,1} vs W_ss,
// 6..8 = {Sg2,Sgd,Sd2} vs W_vv, 9..14 = {ag,ad,bg,bd,g,d} vs W_sv/W_vs.
__global__ void precompute_coeff(
    const float* __restrict__ Wa_s, const float* __restrict__ Wa_v,
    const float* __restrict__ b_a,  const float* __restrict__ Wb_s,
    const float* __restrict__ Wb_v, const float* __restrict__ b_b,
    const float* __restrict__ W_ss, const float* __restrict__ W_vv,
    const float* __restrict__ W_sv, const float* __restrict__ W_vs,
    float* __restrict__ partial)
{
  __shared__ float As[32], Bs[32], Cc[32], Avv[32], Bvv[32];
  __shared__ float red[8][480];
  const int t = threadIdx.x;                     // 256 threads, 32 blocks
  if (t < 32) {
    As[t] = Wa_s[t]; Bs[t] = Wb_s[t]; Cc[t] = b_a[t] + b_b[t];
    Avv[t] = Wa_v[t]; Bvv[t] = Wb_v[t];
  }
  __syncthreads();
  const int w = t & 31;
  const int grp = t >> 5;
  const int chunk = blockIdx.x * 8 + grp;        // 256 chunks x 4 pairs
  float acc[15];
  #pragma unroll
  for (int k = 0; k < 15; ++k) acc[k] = 0.f;
  #pragma unroll
  for (int j = 0; j < 4; ++j) {
    const int p = chunk * 4 + j;                 // pair = u*32+v
    const int u = p >> 5, v = p & 31;
    const float wss = W_ss[p * 32 + w];
    const float wvv = W_vv[p * 32 + w];
    const float wsv = W_sv[p * 32 + w];
    const float wvs = W_vs[p * 32 + w];
    const float au = As[u], bu = Bs[u], cu = Cc[u], pu = Avv[u], qu = Bvv[u];
    const float av = As[v], bv = Bs[v], cv = Cc[v], pv = Avv[v], qv = Bvv[v];
    acc[0]  = fmaf(au * av, wss, acc[0]);
    acc[1]  = fmaf(au * bv + bu * av, wss, acc[1]);
    acc[2]  = fmaf(bu * bv, wss, acc[2]);
    acc[3]  = fmaf(au * cv + cu * av, wss, acc[3]);
    acc[4]  = fmaf(bu * cv + cu * bv, wss, acc[4]);
    acc[5]  = fmaf(cu * cv, wss, acc[5]);
    acc[6]  = fmaf(pu * pv, wvv, acc[6]);
    acc[7]  = fmaf(pu * qv + qu * pv, wvv, acc[7]);
    acc[8]  = fmaf(qu * qv, wvv, acc[8]);
    acc[9]  = fmaf(au * pv, wsv, fmaf(pu * av, wvs, acc[9]));
    acc[10] = fmaf(au * qv, wsv, fmaf(qu * av, wvs, acc[10]));
    acc[11] = fmaf(bu * pv, wsv, fmaf(pu * bv, wvs, acc[11]));
    acc[12] = fmaf(bu * qv, wsv, fmaf(qu * bv, wvs, acc[12]));
    acc[13] = fmaf(cu * pv, wsv, fmaf(pu * cv, wvs, acc[13]));
    acc[14] = fmaf(cu * qv, wsv, fmaf(qu * cv, wvs, acc[14]));
  }
  #pragma unroll
  for (int k = 0; k < 15; ++k) red[grp][k * 32 + w] = acc[k];
  __syncthreads();
  for (int kk = grp; kk < 15; kk += 8) {
    float s = 0.f;
    #pragma unroll
    for (int b = 0; b < 8; ++b) s += red[b][kk * 32 + w];
    partial[blockIdx.x * 480 + kk * 32 + w] = s;
  }
}

// ---------------- precompute 2: reduce partials, fold through Wd ------
__global__ void precompute_M(
    const float* __restrict__ Wd_s, const float* __restrict__ Wd_v,
    const float* __restrict__ partial,
    float* __restrict__ Ms, float* __restrict__ Mv)
{
  __shared__ float cf[480];
  const int t = threadIdx.x;                     // 512 threads, 1 block
  if (t < 480) {
    float s = 0.f;
    for (int b = 0; b < 32; ++b) s += partial[b * 480 + t];
    cf[t] = s;
  }
  __syncthreads();
  if (t < 128) {
    const int f = t;
    float as[9], av[6];
    #pragma unroll
    for (int k = 0; k < 9; ++k) as[k] = 0.f;
    #pragma unroll
    for (int k = 0; k < 6; ++k) av[k] = 0.f;
    for (int w = 0; w < 32; ++w) {
      const float wds = Wd_s[w * 128 + f];
      const float wdv = Wd_v[w * 128 + f];
      #pragma unroll
      for (int k = 0; k < 9; ++k) as[k] = fmaf(cf[k * 32 + w], wds, as[k]);
      #pragma unroll
      for (int k = 0; k < 6; ++k) av[k] = fmaf(cf[(9 + k) * 32 + w], wdv, av[k]);
    }
    const float sP = 1.0f / 4096.0f;                        // PW_DOWN*PW_QQ_S
    const float sQ = 0.57735026918962576451f / 4096.0f;     // *INV_SQRT3
    #pragma unroll
    for (int k = 0; k < 6; ++k) Ms[f * 16 + k] = as[k] * sP;
    #pragma unroll
    for (int k = 0; k < 3; ++k) Ms[f * 16 + 6 + k] = as[6 + k] * sQ;
    #pragma unroll
    for (int k = 0; k < 6; ++k) Mv[f * 8 + k] = av[k] * sQ;
  }
}

// ---------------- main kernel: 64 lanes/node, NT streaming ------------
// Lane l (=t&63) owns features {2l, 2l+1} of its wave's node:
//   s-region : f32x2 at col 2l           -> 64 lanes x 8B contiguous
//   v-region : f32x2 x3 at col 128+6l    -> cols 128+6l..+5 =
//              feature 2l comps (v0[0],v0[1],v1[0]),
//              feature 2l+1 comps (v1[1],v2[0],v2[1])
// Coefficients for the 2 features: 30 loop-invariant regs.
// Depth-1 rotating prefetch under full unroll; all node streams are
// nontemporal (no L2/L3 allocation -> no dirty-victim writebacks from
// the harness's 1-GiB poison fills).
__global__ __launch_bounds__(TBLK, 5) void energy_main(
    const float* __restrict__ nf,
    const float* __restrict__ ch0,
    const float* __restrict__ chi,
    const float* __restrict__ Ms,
    const float* __restrict__ Mv,
    float* __restrict__ out)
{
  static_assert(NPB * (NNODES / NPB) == NNODES, "grid covers all nodes");
  const int t  = threadIdx.x;
  const int l  = t & 63;            // lane = feature-pair owner
  const int wv = t >> 6;            // wave id 0..3 = node slot per pass

  // ---- per-lane loop-invariant coefficients (features 2l, 2l+1) ----
  float ms[2][9];
  float mv[2][6];
  {
    const float4* Ms4 = reinterpret_cast<const float4*>(Ms);  // [128][4]
    const float4* Mv4 = reinterpret_cast<const float4*>(Mv);  // [128][2]
    #pragma unroll
    for (int fl = 0; fl < 2; ++fl) {
      const int f = 2 * l + fl;
      const float4 a = Ms4[f * 4 + 0];
      const float4 b = Ms4[f * 4 + 1];
      const float4 c = Ms4[f * 4 + 2];
      ms[fl][0] = a.x; ms[fl][1] = a.y; ms[fl][2] = a.z; ms[fl][3] = a.w;
      ms[fl][4] = b.x; ms[fl][5] = b.y; ms[fl][6] = b.z; ms[fl][7] = b.w;
      ms[fl][8] = c.x;
      const float4 u = Mv4[f * 2 + 0];
      const float4 v = Mv4[f * 2 + 1];
      mv[fl][0] = u.x; mv[fl][1] = u.y; mv[fl][2] = u.z; mv[fl][3] = u.w;
      mv[fl][4] = v.x; mv[fl][5] = v.y;
    }
  }

  const f32x2* nf2 = reinterpret_cast<const f32x2*>(nf);     // 256 per row
  const f32x4* c04 = reinterpret_cast<const f32x4*>(ch0);
  const f32x4* ci4 = reinterpret_cast<const f32x4*>(chi);

  const int node0 = blockIdx.x * NPB;
  const int voff  = 64 + 3 * l;     // f32x2 index of v base (col 128+6l)

  f32x2 pxs, pv0, pv1, pv2;
  f32x4 pc0, pci;

#define LOADSET(pp) do {                                             \
    const int nn_    = node0 + (pp) * WAVES_PER_BLK + wv;            \
    const size_t rb2 = (size_t)nn_ * 256;                            \
    pc0 = __builtin_nontemporal_load(c04 + nn_);                     \
    pci = __builtin_nontemporal_load(ci4 + nn_);                     \
    pxs = __builtin_nontemporal_load(nf2 + rb2 + l);                 \
    pv0 = __builtin_nontemporal_load(nf2 + rb2 + voff + 0);          \
    pv1 = __builtin_nontemporal_load(nf2 + rb2 + voff + 1);          \
    pv2 = __builtin_nontemporal_load(nf2 + rb2 + voff + 2);          \
  } while (0)

  // ---- prologue: pass 0 in flight ----
  LOADSET(0);

  #pragma unroll
  for (int p = 0; p < PASSES; ++p) {
    // consume current set (SSA-renamed under full unroll), refill for p+1
    const f32x2 xs  = pxs;
    const f32x2 xv0 = pv0;
    const f32x2 xv1 = pv1;
    const f32x2 xv2 = pv2;
    const f32x4 cc0 = pc0;
    const f32x4 cci = pci;
    if (p + 1 < PASSES) LOADSET(p + 1);

    const int node = node0 + p * WAVES_PER_BLK + wv;

    const float alpha = cci[0], g0 = cci[1], g1 = cci[2], g2 = cci[3];
    const float beta  = cc0[0], d0 = cc0[1], d1 = cc0[2], d2 = cc0[3];
    const float m0 = alpha * alpha, m1 = alpha * beta, m2 = beta * beta;
    const float m6 = fmaf(g0, g0, fmaf(g1, g1, g2 * g2));
    const float m7 = fmaf(g0, d0, fmaf(g1, d1, g2 * d2));
    const float m8 = fmaf(d0, d0, fmaf(d1, d1, d2 * d2));

    float e = 0.f;

    // ---- s-region: 2 features ----
    const float xse[2] = {xs[0], xs[1]};
    #pragma unroll
    for (int fl = 0; fl < 2; ++fl) {
      float r = ms[fl][5];
      r = fmaf(m0,    ms[fl][0], r);
      r = fmaf(m1,    ms[fl][1], r);
      r = fmaf(m2,    ms[fl][2], r);
      r = fmaf(alpha, ms[fl][3], r);
      r = fmaf(beta,  ms[fl][4], r);
      r = fmaf(m6,    ms[fl][6], r);
      r = fmaf(m7,    ms[fl][7], r);
      r = fmaf(m8,    ms[fl][8], r);
      e = fmaf(xse[fl], r, e);
    }

    // ---- v-region: 2 whole features, components split across f32x2s --
    const float xva[2][3] = {{xv0[0], xv0[1], xv1[0]},
                             {xv1[1], xv2[0], xv2[1]}};
    #pragma unroll
    for (int fl = 0; fl < 2; ++fl) {
      const float P = fmaf(g0, xva[fl][0], fmaf(g1, xva[fl][1], g2 * xva[fl][2]));
      const float Q = fmaf(d0, xva[fl][0], fmaf(d1, xva[fl][1], d2 * xva[fl][2]));
      const float wP = fmaf(alpha, mv[fl][0], fmaf(beta, mv[fl][2], mv[fl][4]));
      const float wQ = fmaf(alpha, mv[fl][1], fmaf(beta, mv[fl][3], mv[fl][5]));
      e = fmaf(P, wP, fmaf(Q, wQ, e));
    }

    // ---- reduce across the full 64-lane wave ----
    e += __shfl_xor(e, 1);
    e += __shfl_xor(e, 2);
    e += __shfl_xor(e, 4);
    e += __shfl_xor(e, 8);
    e += __shfl_xor(e, 16);
    e += __shfl_xor(e, 32);
    if (l == 0) __builtin_nontemporal_store(e, out + node);
  }
#undef LOADSET
}

// ---------------- launcher -------------------------------------------
extern "C" void kernel_launch(void* const* d_in, const int* in_sizes, int n_in,
                              void* d_out, int out_size, void* d_ws, size_t ws_size,
                              hipStream_t stream)
{
  const float* node_feats      = (const float*)d_in[0];
  const float* charges_0       = (const float*)d_in[1];
  const float* charges_induced = (const float*)d_in[2];
  const float* Wa_s = (const float*)d_in[8];
  const float* Wa_v = (const float*)d_in[9];
  const float* b_a  = (const float*)d_in[10];
  const float* Wb_s = (const float*)d_in[11];
  const float* Wb_v = (const float*)d_in[12];
  const float* b_b  = (const float*)d_in[13];
  const float* W_ss = (const float*)d_in[14];
  const float* W_vv = (const float*)d_in[15];
  const float* W_sv = (const float*)d_in[16];
  const float* W_vs = (const float*)d_in[17];
  const float* Wd_s = (const float*)d_in[18];
  const float* Wd_v = (const float*)d_in[19];

  float* ws      = (float*)d_ws;
  float* Ms      = ws;              // [128][16] = 2048 floats
  float* Mv      = ws + 2048;       // [128][8]  = 1024 floats
  float* partial = ws + 3072;       // [32][15][32] = 15360 floats

  precompute_coeff<<<32, 256, 0, stream>>>(Wa_s, Wa_v, b_a, Wb_s, Wb_v, b_b,
                                           W_ss, W_vv, W_sv, W_vs, partial);
  precompute_M<<<1, 512, 0, stream>>>(Wd_s, Wd_v, partial, Ms, Mv);
  energy_main<<<NNODES / NPB, TBLK, 0, stream>>>(node_feats, charges_0,
                                                 charges_induced, Ms, Mv,
                                                 (float*)d_out);
}